// Round 1
// baseline (340.882 us; speedup 1.0000x reference)
//
#include <hip/hip_runtime.h>
#include <hip/hip_bf16.h>
#include <cstdint>

// GateAttention fused pipeline, bf16-MFMA implementation.
// B=16, LC=2048, LQ=256, D=768, F=768.
//
// ws layout (bf16 elements):
//   WCt  [768][768]    (WC^T)
//   WQt  [768][768]    (WQ^T)
//   Vt   [768][1536]   (V^T)
//   xqB  [4096][768]   (x_ques bf16, row-major)
//   xqT  [16][768][256] (x_ques^T per batch)
//   xqW  [4096][768]   relu(x_ques@WQ)
//   xcW  [32768][768]  relu(x_cont@WC)
//   res  [32768][1536] [x_cont | C] bf16
// total ~174.6 MB

using bf16 = __hip_bfloat16;
typedef __attribute__((ext_vector_type(8))) __bf16 bf16x8;
typedef __attribute__((ext_vector_type(4))) float f32x4;

typedef __attribute__((address_space(1))) const uint32_t GU32;
typedef __attribute__((address_space(3))) uint32_t LU32;

__device__ __forceinline__ void gll16(const bf16* g, bf16* l) {
  __builtin_amdgcn_global_load_lds((GU32*)g, (LU32*)l, 16, 0, 0);
}

__device__ __forceinline__ f32x4 mfma_bf16(bf16x8 a, bf16x8 b, f32x4 c) {
  return __builtin_amdgcn_mfma_f32_16x16x32_bf16(a, b, c, 0, 0, 0);
}

__device__ __forceinline__ bf16x8 ld_frag(const bf16* p) {
  return *reinterpret_cast<const bf16x8*>(p);
}

// ---------- transpose f32 [R][C] -> bf16 [C][R], batched ----------
__global__ void transpose_f32_bf16(const float* __restrict__ in, bf16* __restrict__ out,
                                   int R, int C, long ibs, long obs) {
  __shared__ float tile[32][33];
  const float* inb = in + (long)blockIdx.z * ibs;
  bf16* outb = out + (long)blockIdx.z * obs;
  int c0 = blockIdx.x * 32, r0 = blockIdx.y * 32;
  int tx = threadIdx.x, ty = threadIdx.y;
#pragma unroll
  for (int i = ty; i < 32; i += 8)
    tile[i][tx] = inb[(long)(r0 + i) * C + (c0 + tx)];
  __syncthreads();
#pragma unroll
  for (int i = ty; i < 32; i += 8)
    outb[(long)(c0 + i) * R + (r0 + tx)] = __float2bfloat16(tile[tx][i]);
}

// ---------- elementwise f32 -> bf16 with output row stride ----------
__global__ void convert_f32_bf16(const float* __restrict__ in, bf16* __restrict__ out,
                                 int cols, int ldo, long n4) {
  long i = (long)blockIdx.x * blockDim.x + threadIdx.x;
  if (i >= n4) return;
  long idx = i * 4;
  float4 v = *reinterpret_cast<const float4*>(in + idx);
  long row = idx / cols;
  int col = (int)(idx - row * cols);
  bf16* o = out + row * (long)ldo + col;
  o[0] = __float2bfloat16(v.x);
  o[1] = __float2bfloat16(v.y);
  o[2] = __float2bfloat16(v.z);
  o[3] = __float2bfloat16(v.w);
}

// ---------- GEMM: C = epi(A[M,K] * Bt[N,K]^T), 128x128 tile, BK=32 ----------
// EPI: 0 none, 1 relu, 2 sigmoid. OT: bf16 or float.
template <int EPI, typename OT>
__global__ __launch_bounds__(256) void gemm_bt(
    const bf16* __restrict__ A, long lda,
    const bf16* __restrict__ Bt, long ldb,
    OT* __restrict__ Co, long ldc, int K) {
  __shared__ __align__(16) bf16 As[128 * 32];
  __shared__ __align__(16) bf16 Bs[128 * 32];
  const int tid = threadIdx.x;
  const int wave = tid >> 6;
  const int lane = tid & 63;
  const int l16 = lane & 15;
  const int kh = lane >> 4;
  const int wm = (wave >> 1) * 64;
  const int wn = (wave & 1) * 64;
  const long row0 = (long)blockIdx.x * 128;
  const long col0 = (long)blockIdx.y * 128;
  const int srow = tid >> 2;
  const int scol = (tid & 3) * 8;

  const bf16* ap0 = A + (row0 + srow) * lda + scol;
  const bf16* ap1 = ap0 + 64 * lda;
  const bf16* bp0 = Bt + (col0 + srow) * ldb + scol;
  const bf16* bp1 = bp0 + 64 * ldb;
  bf16* as0 = As + wave * 512;
  bf16* as1 = as0 + 2048;
  bf16* bs0 = Bs + wave * 512;
  bf16* bs1 = bs0 + 2048;

  f32x4 acc[4][4] = {};

  for (int k0 = 0; k0 < K; k0 += 32) {
    gll16(ap0 + k0, as0);
    gll16(ap1 + k0, as1);
    gll16(bp0 + k0, bs0);
    gll16(bp1 + k0, bs1);
    __syncthreads();
    bf16x8 af[4], bfr[4];
#pragma unroll
    for (int i = 0; i < 4; ++i)
      af[i] = ld_frag(As + (wm + i * 16 + l16) * 32 + kh * 8);
#pragma unroll
    for (int j = 0; j < 4; ++j)
      bfr[j] = ld_frag(Bs + (wn + j * 16 + l16) * 32 + kh * 8);
#pragma unroll
    for (int i = 0; i < 4; ++i)
#pragma unroll
      for (int j = 0; j < 4; ++j)
        acc[i][j] = mfma_bf16(af[i], bfr[j], acc[i][j]);
    __syncthreads();
  }

#pragma unroll
  for (int i = 0; i < 4; ++i)
#pragma unroll
    for (int j = 0; j < 4; ++j)
#pragma unroll
      for (int r = 0; r < 4; ++r) {
        long row = row0 + wm + i * 16 + kh * 4 + r;
        long col = col0 + wn + j * 16 + l16;
        float v = acc[i][j][r];
        if constexpr (EPI == 1) v = fmaxf(v, 0.0f);
        if constexpr (EPI == 2) v = 1.0f / (1.0f + expf(-v));
        if constexpr (sizeof(OT) == 2)
          Co[row * ldc + col] = __float2bfloat16(v);
        else
          Co[row * ldc + col] = (float)v;
      }
}

// ---------- fused attention: per (b, 64-row c-tile) ----------
// S = xcW_tile @ xqW[b]^T * scale + mask ; P = softmax(S) ; C = P @ xq[b]
// writes C into right half of res.
__global__ __launch_bounds__(256) void attn_kernel(
    const bf16* __restrict__ xcW, const bf16* __restrict__ xqW,
    const bf16* __restrict__ xqT, const int* __restrict__ qlen_arr,
    bf16* __restrict__ res) {
  __shared__ __align__(16) bf16 As[64 * 32];
  __shared__ __align__(16) bf16 Bs[256 * 32];
  __shared__ __align__(16) bf16 P[64 * 264];  // padded stride 264
  __shared__ float wred[64][4];
  __shared__ float wsum[64][4];

  const int b = blockIdx.y;
  const int ct = blockIdx.x;
  const int tid = threadIdx.x;
  const int wave = tid >> 6;
  const int lane = tid & 63;
  const int l16 = lane & 15;
  const int kh = lane >> 4;

  const long crow0 = (long)b * 2048 + (long)ct * 64;
  const int srow = tid >> 2;
  const int scol = (tid & 3) * 8;

  const bf16* ap = xcW + (crow0 + srow) * 768 + scol;
  const bf16* bp = xqW + ((long)b * 256 + srow) * 768 + scol;

  f32x4 acc[4][4] = {};
  for (int k0 = 0; k0 < 768; k0 += 32) {
    gll16(ap + k0, As + wave * 512);
    gll16(bp + k0, Bs + wave * 512);
    gll16(bp + 64 * 768 + k0, Bs + 2048 + wave * 512);
    gll16(bp + 128 * 768 + k0, Bs + 4096 + wave * 512);
    gll16(bp + 192 * 768 + k0, Bs + 6144 + wave * 512);
    __syncthreads();
    bf16x8 af[4], bfr[4];
#pragma unroll
    for (int i = 0; i < 4; ++i)
      af[i] = ld_frag(As + (i * 16 + l16) * 32 + kh * 8);
#pragma unroll
    for (int j = 0; j < 4; ++j)
      bfr[j] = ld_frag(Bs + (wave * 64 + j * 16 + l16) * 32 + kh * 8);
#pragma unroll
    for (int i = 0; i < 4; ++i)
#pragma unroll
      for (int j = 0; j < 4; ++j)
        acc[i][j] = mfma_bf16(af[i], bfr[j], acc[i][j]);
    __syncthreads();
  }

  const float scale = 0.036084391824351615f;  // 1/sqrt(768)
  const int qlen = qlen_arr[b];

  // scale + mask in place (matches ref: logits/sqrt(F) + (-1e12 on j>=qlen))
#pragma unroll
  for (int i = 0; i < 4; ++i)
#pragma unroll
    for (int j = 0; j < 4; ++j) {
      int col = wave * 64 + j * 16 + l16;
      float m = (col >= qlen) ? -1.0e12f : 0.0f;
#pragma unroll
      for (int r = 0; r < 4; ++r)
        acc[i][j][r] = acc[i][j][r] * scale + m;
    }

  // per-wave row max -> cross-wave via LDS
#pragma unroll
  for (int i = 0; i < 4; ++i)
#pragma unroll
    for (int r = 0; r < 4; ++r) {
      float mx = fmaxf(fmaxf(acc[i][0][r], acc[i][1][r]),
                       fmaxf(acc[i][2][r], acc[i][3][r]));
      mx = fmaxf(mx, __shfl_xor(mx, 1));
      mx = fmaxf(mx, __shfl_xor(mx, 2));
      mx = fmaxf(mx, __shfl_xor(mx, 4));
      mx = fmaxf(mx, __shfl_xor(mx, 8));
      if (l16 == 0) wred[i * 16 + kh * 4 + r][wave] = mx;
    }
  __syncthreads();

  // exp + per-wave row sum
#pragma unroll
  for (int i = 0; i < 4; ++i)
#pragma unroll
    for (int r = 0; r < 4; ++r) {
      int row = i * 16 + kh * 4 + r;
      float gm = fmaxf(fmaxf(wred[row][0], wred[row][1]),
                       fmaxf(wred[row][2], wred[row][3]));
      float s = 0.0f;
#pragma unroll
      for (int j = 0; j < 4; ++j) {
        float e = expf(acc[i][j][r] - gm);
        acc[i][j][r] = e;
        s += e;
      }
      s += __shfl_xor(s, 1);
      s += __shfl_xor(s, 2);
      s += __shfl_xor(s, 4);
      s += __shfl_xor(s, 8);
      if (l16 == 0) wsum[row][wave] = s;
    }
  __syncthreads();

  // normalize, write P (bf16)
#pragma unroll
  for (int i = 0; i < 4; ++i)
#pragma unroll
    for (int r = 0; r < 4; ++r) {
      int row = i * 16 + kh * 4 + r;
      float inv = 1.0f / (wsum[row][0] + wsum[row][1] + wsum[row][2] + wsum[row][3]);
#pragma unroll
      for (int j = 0; j < 4; ++j)
        P[row * 264 + wave * 64 + j * 16 + l16] = __float2bfloat16(acc[i][j][r] * inv);
    }
  __syncthreads();

  // PV: C_tile = P @ xq[b]  (B operand = xqT[b][d][q], gemm_bt form)
  for (int nb = 0; nb < 3; ++nb) {
    const int n0 = nb * 256 + wave * 64;
    const bf16* btp = xqT + ((long)b * 768 + n0) * 256;
    f32x4 a2[4][4] = {};
#pragma unroll
    for (int kk = 0; kk < 256; kk += 32) {
      bf16x8 pf[4], vf[4];
#pragma unroll
      for (int i = 0; i < 4; ++i)
        pf[i] = ld_frag(P + (i * 16 + l16) * 264 + kk + kh * 8);
#pragma unroll
      for (int j = 0; j < 4; ++j)
        vf[j] = ld_frag(btp + (j * 16 + l16) * 256 + kk + kh * 8);
#pragma unroll
      for (int i = 0; i < 4; ++i)
#pragma unroll
        for (int j = 0; j < 4; ++j)
          a2[i][j] = mfma_bf16(pf[i], vf[j], a2[i][j]);
    }
#pragma unroll
    for (int i = 0; i < 4; ++i)
#pragma unroll
      for (int j = 0; j < 4; ++j)
#pragma unroll
        for (int r = 0; r < 4; ++r) {
          long row = crow0 + i * 16 + kh * 4 + r;
          int col = n0 + j * 16 + l16;
          res[row * 1536 + 768 + col] = __float2bfloat16(a2[i][j][r]);
        }
  }
}

extern "C" void kernel_launch(void* const* d_in, const int* in_sizes, int n_in,
                              void* d_out, int out_size, void* d_ws, size_t ws_size,
                              hipStream_t stream) {
  const float* x_cont = (const float*)d_in[0];  // [16,2048,768]
  const float* x_ques = (const float*)d_in[1];  // [16,256,768]
  const int* ques_len = (const int*)d_in[2];    // [16]
  const float* WC = (const float*)d_in[3];      // [768,768]
  const float* WQ = (const float*)d_in[4];      // [768,768]
  const float* V = (const float*)d_in[5];       // [1536,768]
  float* out = (float*)d_out;                   // [32768,768]

  bf16* WCt = (bf16*)d_ws;                      // [768][768]
  bf16* WQt = WCt + (long)768 * 768;            // [768][768]
  bf16* Vt = WQt + (long)768 * 768;             // [768][1536]
  bf16* xqB = Vt + (long)768 * 1536;            // [4096][768]
  bf16* xqT = xqB + (long)4096 * 768;           // [16][768][256]
  bf16* xqW = xqT + (long)16 * 768 * 256;       // [4096][768]
  bf16* xcW = xqW + (long)4096 * 768;           // [32768][768]
  bf16* res = xcW + (long)32768 * 768;          // [32768][1536]

  // weight / input conversions
  transpose_f32_bf16<<<dim3(24, 24, 1), dim3(32, 8), 0, stream>>>(WC, WCt, 768, 768, 0, 0);
  transpose_f32_bf16<<<dim3(24, 24, 1), dim3(32, 8), 0, stream>>>(WQ, WQt, 768, 768, 0, 0);
  transpose_f32_bf16<<<dim3(24, 48, 1), dim3(32, 8), 0, stream>>>(V, Vt, 1536, 768, 0, 0);
  transpose_f32_bf16<<<dim3(24, 8, 16), dim3(32, 8), 0, stream>>>(
      x_ques, xqT, 256, 768, (long)256 * 768, (long)768 * 256);
  convert_f32_bf16<<<3072, 256, 0, stream>>>(x_ques, xqB, 768, 768, (long)4096 * 768 / 4);
  convert_f32_bf16<<<24576, 256, 0, stream>>>(x_cont, res, 768, 1536, (long)32768 * 768 / 4);

  // projections
  gemm_bt<1, bf16><<<dim3(32, 6), 256, 0, stream>>>(xqB, 768, WQt, 768, xqW, 768, 768);
  gemm_bt<1, bf16><<<dim3(256, 6), 256, 0, stream>>>(res, 1536, WCt, 768, xcW, 768, 768);

  // attention -> C into right half of res
  attn_kernel<<<dim3(32, 16), 256, 0, stream>>>(xcW, xqW, xqT, ques_len, res);

  // gate = sigmoid(res @ V)
  gemm_bt<2, float><<<dim3(256, 6), 256, 0, stream>>>(res, 1536, Vt, 1536, out, 768, 1536);
}